// Round 4
// baseline (148.274 us; speedup 1.0000x reference)
//
#include <hip/hip_runtime.h>

typedef unsigned short u16;
typedef unsigned int u32;
typedef __attribute__((ext_vector_type(8))) __bf16 bf16x8;
typedef __attribute__((ext_vector_type(4))) float f32x4;

constexpr int NM = 8;

// ---- workspace layout (float offsets), ~8.1 MB ----
constexpr size_t OFF_PI  = 0;                        // pi fp32 [m][64]
constexpr size_t OFF_PBH = 512;                      // P hi bf16 [e][m][c][d] (u16)
constexpr size_t OFF_PBL = OFF_PBH + 1015808;        // P lo

union FR { uint4 u; bf16x8 v; };

// split x -> hi (RNE bf16) + lo (trunc bf16 of residual)
__device__ __forceinline__ void split_bf16(float x, u16& h, u16& l) {
  u32 b = __float_as_uint(x);
  u32 hb = (b + 0x7fffu + ((b >> 16) & 1u)) & 0xffff0000u;
  h = (u16)(hb >> 16);
  float r = x - __uint_as_float(hb);
  l = (u16)(__float_as_uint(r) >> 16);
}

// 8 fp32 (two float4, k-order) -> packed bf16 hi/lo fragments
__device__ __forceinline__ void split8(const float4 a, const float4 b,
                                       uint4& hi, uint4& lo) {
  u16 h[8], l[8];
  split_bf16(a.x, h[0], l[0]); split_bf16(a.y, h[1], l[1]);
  split_bf16(a.z, h[2], l[2]); split_bf16(a.w, h[3], l[3]);
  split_bf16(b.x, h[4], l[4]); split_bf16(b.y, h[5], l[5]);
  split_bf16(b.z, h[6], l[6]); split_bf16(b.w, h[7], l[7]);
  hi.x = h[0] | ((u32)h[1] << 16); hi.y = h[2] | ((u32)h[3] << 16);
  hi.z = h[4] | ((u32)h[5] << 16); hi.w = h[6] | ((u32)h[7] << 16);
  lo.x = l[0] | ((u32)l[1] << 16); lo.y = l[2] | ((u32)l[3] << 16);
  lo.z = l[4] | ((u32)l[5] << 16); lo.w = l[6] | ((u32)l[7] << 16);
}

// triple-product split-bf16 MFMA: a += Ah*Bh + Ah*Bl + Al*Bh
__device__ __forceinline__ void mfma3(f32x4& a, const uint4 ah, const uint4 al,
                                      const uint4 bh, const uint4 bl) {
  FR Ah, Al, Bh, Bl;
  Ah.u = ah; Al.u = al; Bh.u = bh; Bl.u = bl;
  a = __builtin_amdgcn_mfma_f32_16x16x32_bf16(Ah.v, Bh.v, a, 0, 0, 0);
  a = __builtin_amdgcn_mfma_f32_16x16x32_bf16(Ah.v, Bl.v, a, 0, 0, 0);
  a = __builtin_amdgcn_mfma_f32_16x16x32_bf16(Al.v, Bh.v, a, 0, 0, 0);
}

// ---------------- K1: per-(e,m) block: build Q, Horner P=expm(tQ) via MFMA ----
// X^T stored in LDS as bf16 hi/lo (split at write); A = tQ frags persist in regs.
__global__ __launch_bounds__(256, 4) void k_pmats(
    const float* __restrict__ R_inv, const float* __restrict__ pi_inv,
    const float* __restrict__ lengths, float* __restrict__ ws,
    u16* __restrict__ PBH, u16* __restrict__ PBL) {
  const int e = blockIdx.x, m = blockIdx.y;
  const int tid = threadIdx.x, lane = tid & 63, w = tid >> 6;
  const int ln = lane & 15, kq = lane >> 4;
  __shared__ float pis[64];
  __shared__ float n2s;
  __shared__ float Qs[64 * 68];
  __shared__ u32 XT[4096];  // X^T: row n (64) x 32 dwords hi; +2048 lo

  if (tid < 64) {
    float p = (tid < 63) ? pi_inv[m * 63 + tid] : 0.f;
    float v = p * p;
    #pragma unroll
    for (int off = 32; off; off >>= 1) v += __shfl_down(v, off, 64);
    if (tid == 0) n2s = v;
  }
  __syncthreads();
  const float n2 = n2s;
  if (tid < 64) {
    const float den = n2 + 1.f;
    const float x = (tid < 63) ? 2.f * pi_inv[m * 63 + tid] / den
                               : (n2 - 1.f) / den;
    const float pv = x * x;
    pis[tid] = pv;
    if (e == 0) ws[OFF_PI + (size_t)m * 64 + tid] = pv;
  }
  __syncthreads();
  for (int idx = tid; idx < 4096; idx += 256) {
    const int i = idx >> 6, j = idx & 63;
    float q = 0.f;
    if (i != j) {
      const int a = min(i, j), b = max(i, j);
      const int kk = a * (127 - a) / 2 + (b - a - 1);
      q = expf(R_inv[m * 2016 + kk]) * pis[j];
    }
    Qs[i * 68 + j] = q;
  }
  // X = I (chunk-swizzled bf16), independent of Qs
  {
    const int n = tid & 63, cp = (tid >> 6) * 2;
    #pragma unroll
    for (int ci = 0; ci < 2; ++ci) {
      const int c = cp + ci;
      uint4 hv = {0, 0, 0, 0};
      const int r = n - 8 * c;
      if (r >= 0 && r < 8) {
        const u32 val = (u32)0x3F80u << ((r & 1) * 16);
        if (r < 2) hv.x = val; else if (r < 4) hv.y = val;
        else if (r < 6) hv.z = val; else hv.w = val;
      }
      const int dw = n * 32 + (((c + n) & 7) << 2);
      *(uint4*)&XT[dw] = hv;
      uint4 zz = {0, 0, 0, 0};
      *(uint4*)&XT[2048 + dw] = zz;
    }
  }
  __syncthreads();
  if (tid < 64) {
    float s = 0.f;
    #pragma unroll 4
    for (int j4 = 0; j4 < 64; j4 += 4) {
      const float4 q = *(const float4*)&Qs[tid * 68 + j4];
      s += q.x + q.y + q.z + q.w;
    }
    Qs[tid * 68 + tid] = -s;
  }
  __syncthreads();
  // A-frags = rows [16w+ln] of t*Q, split hi/lo, persist
  const float t = lengths[e];
  uint4 ah[2], al[2];
  #pragma unroll
  for (int kh = 0; kh < 2; ++kh) {
    const float* qr = &Qs[(16 * w + ln) * 68 + kh * 32 + kq * 8];
    float4 a = *(const float4*)qr, b = *(const float4*)(qr + 4);
    a.x *= t; a.y *= t; a.z *= t; a.w *= t;
    b.x *= t; b.y *= t; b.z *= t; b.w *= t;
    split8(a, b, ah[kh], al[kh]);
  }
  const f32x4 z = {0.f, 0.f, 0.f, 0.f};
  const size_t pb = ((size_t)e * 8 + m) << 12;
  const int i0 = 16 * w + 4 * kq;
  for (int k = 12; k >= 1; --k) {
    __syncthreads();  // X ready
    f32x4 acc[4] = {z, z, z, z};
    #pragma unroll
    for (int bt = 0; bt < 4; ++bt) {
      const int n = bt * 16 + ln;
      #pragma unroll
      for (int kh = 0; kh < 2; ++kh) {
        const int dw = n * 32 + ((((kh * 4 + kq) + n) & 7) << 2);
        const uint4 bh = *(const uint4*)&XT[dw];
        const uint4 bl = *(const uint4*)&XT[2048 + dw];
        mfma3(acc[bt], ah[kh], al[kh], bh, bl);
      }
    }
    __syncthreads();  // all reads done before overwrite
    const float rk = 1.f / (float)k;
    if (k > 1) {
      #pragma unroll
      for (int bt = 0; bt < 4; ++bt) {
        const int n = bt * 16 + ln;
        float v[4] = {acc[bt].x * rk, acc[bt].y * rk, acc[bt].z * rk,
                      acc[bt].w * rk};
        #pragma unroll
        for (int r = 0; r < 4; ++r)
          if (i0 + r == n) v[r] += 1.f;
        u16 h[4], l[4];
        split_bf16(v[0], h[0], l[0]); split_bf16(v[1], h[1], l[1]);
        split_bf16(v[2], h[2], l[2]); split_bf16(v[3], h[3], l[3]);
        const int dw =
            n * 32 + ((((2 * w + (kq >> 1)) + n) & 7) << 2) + (kq & 1) * 2;
        uint2 hh, llv;
        hh.x = h[0] | ((u32)h[1] << 16); hh.y = h[2] | ((u32)h[3] << 16);
        llv.x = l[0] | ((u32)l[1] << 16); llv.y = l[2] | ((u32)l[3] << 16);
        *(uint2*)&XT[dw] = hh;
        *(uint2*)&XT[2048 + dw] = llv;
      }
    } else {
      // final: P = I + C; write straight to global from C-frags
      #pragma unroll
      for (int bt = 0; bt < 4; ++bt) {
        const int n = bt * 16 + ln;
        float v[4] = {acc[bt].x, acc[bt].y, acc[bt].z, acc[bt].w};
        #pragma unroll
        for (int r = 0; r < 4; ++r)
          if (i0 + r == n) v[r] += 1.f;
        #pragma unroll
        for (int r = 0; r < 4; ++r) {
          u16 h, l;
          split_bf16(v[r], h, l);
          const size_t o = pb + (size_t)(i0 + r) * 64 + n;
          PBH[o] = h;
          PBL[o] = l;
        }
      }
    }
  }
}

// ---------------- K2: fully-fused tree + final dot ----------------
// 512 blocks = (m = blk&7 [== XCD id], btile of 16 cols) x 8 waves.
// Node slots: fp32 [b(16 rows)][d(64)], 16-chunk XOR swizzle -> conflict-free
// b128 read/write. 16 slots x 4KB = 64KB -> 2 blocks/CU.
__global__ __launch_bounds__(512, 4) void k_tree(
    const float* __restrict__ leaves, const u16* __restrict__ Phi,
    const u16* __restrict__ Plo, const float* __restrict__ ws,
    float* __restrict__ out) {
  const int m = blockIdx.x & 7, btile = blockIdx.x >> 3;
  const int tid = threadIdx.x, lane = tid & 63, w = tid >> 6;
  const int ln = lane & 15, kq = lane >> 4;
  __shared__ float slots[16384];
  __shared__ float part[4][16];
  const f32x4 z = {0.f, 0.f, 0.f, 0.f};

  auto do_pair = [&](int p, int eb, int shift, int out_slot, int ct0, int nct,
                     bool leaf, f32x4* rootout) {
    uint4 bh[2], bl[2];
    f32x4 acc0[4], acc1[4];
    for (int s = 0; s < 2; ++s) {
      // B fragments (prev) from leaves or fp32 LDS slots; split to hi/lo
      #pragma unroll
      for (int kh = 0; kh < 2; ++kh) {
        float4 xa, xb;
        if (leaf) {
          const float* g = leaves + (size_t)(btile * 16 + ln) * 2048 +
                           (size_t)(eb + 2 * p + s) * 64 + kh * 32 + kq * 8;
          xa = *(const float4*)g;
          xb = *(const float4*)(g + 4);
        } else {
          const float* nb = slots + ((2 * p + s) << shift) * 1024 + ln * 64;
          const int cj = kh * 8 + kq * 2;
          xa = *(const float4*)&nb[((cj + ln) & 15) << 2];
          xb = *(const float4*)&nb[((cj + 1 + ln) & 15) << 2];
        }
        split8(xa, xb, bh[kh], bl[kh]);
      }
      // A fragments (P rows) from global, MFMA accumulate
      const size_t pbase = ((size_t)(eb + 2 * p + s) * 8 + m) << 12;
      f32x4* acc = s ? acc1 : acc0;
      #pragma unroll 4
      for (int ci = 0; ci < nct; ++ci) {
        const int ct = ct0 + ci;
        f32x4 a = z;
        #pragma unroll
        for (int kh = 0; kh < 2; ++kh) {
          const size_t off = pbase + (size_t)(ct * 16 + ln) * 64 + kh * 32 + kq * 8;
          const uint4 pah = *(const uint4*)(Phi + off);
          const uint4 pal = *(const uint4*)(Plo + off);
          mfma3(a, pah, pal, bh[kh], bl[kh]);
        }
        acc[ci] = a;
      }
    }
    // sibling product -> fp32 node write (single b128) or root return
    #pragma unroll 4
    for (int ci = 0; ci < nct; ++ci) {
      f32x4 pr;
      pr.x = acc0[ci].x * acc1[ci].x;
      pr.y = acc0[ci].y * acc1[ci].y;
      pr.z = acc0[ci].z * acc1[ci].z;
      pr.w = acc0[ci].w * acc1[ci].w;
      if (rootout) {
        *rootout = pr;
      } else {
        const int ct = ct0 + ci;
        float* nb = slots + out_slot * 1024 + ln * 64;
        *(float4*)&nb[(((ct * 4 + kq) + ln) & 15) << 2] =
            make_float4(pr.x, pr.y, pr.z, pr.w);
      }
    }
  };

  // L0: 16 pairs (leaves) -> slots 0..15
  do_pair(w, 0, 0, w, 0, 4, true, nullptr);
  do_pair(w + 8, 0, 0, w + 8, 0, 4, true, nullptr);
  __syncthreads();
  // L1: 8 pairs, slots (2p,2p+1) -> 2p
  do_pair(w, 32, 0, 2 * w, 0, 4, false, nullptr);
  __syncthreads();
  // L2: 4 pairs x 2 ct-halves, slots (4p,4p+2) -> 4p
  do_pair(w >> 1, 48, 1, 4 * (w >> 1), (w & 1) * 2, 2, false, nullptr);
  __syncthreads();
  // L3: 2 pairs x 4 ct, slots (8p,8p+4) -> 8p
  do_pair(w >> 2, 56, 2, 8 * (w >> 2), w & 3, 1, false, nullptr);
  __syncthreads();
  // L4 root: slots (0,8); waves 0..3, ct=w; fused dot with pi
  if (w < 4) {
    f32x4 prod = z;
    do_pair(0, 60, 3, -1, w, 1, false, &prod);
    const float4 piv =
        *(const float4*)&ws[OFF_PI + (size_t)m * 64 + w * 16 + kq * 4];
    float v = prod.x * piv.x + prod.y * piv.y + prod.z * piv.z + prod.w * piv.w;
    v += __shfl_xor(v, 16, 64);
    v += __shfl_xor(v, 32, 64);
    if (lane < 16) part[w][lane] = v;
  }
  __syncthreads();
  if (tid < 16)
    out[(size_t)(btile * 16 + tid) * 8 + m] =
        part[0][tid] + part[1][tid] + part[2][tid] + part[3][tid];
}

extern "C" void kernel_launch(void* const* d_in, const int* in_sizes, int n_in,
                              void* d_out, int out_size, void* d_ws, size_t ws_size,
                              hipStream_t stream) {
  const float* leaves  = (const float*)d_in[0];  // (B, 32, 64)
  const float* R_inv   = (const float*)d_in[1];  // (8, 2016)
  const float* pi_inv  = (const float*)d_in[2];  // (8, 63)
  const float* lengths = (const float*)d_in[3];  // (62,)
  float* out = (float*)d_out;                    // (B, 8)
  float* ws  = (float*)d_ws;

  u16* PBH = (u16*)(ws + OFF_PBH);
  u16* PBL = (u16*)(ws + OFF_PBL);

  hipLaunchKernelGGL(k_pmats, dim3(62, NM), dim3(256), 0, stream, R_inv, pi_inv,
                     lengths, ws, PBH, PBL);
  hipLaunchKernelGGL(k_tree, dim3(512), dim3(512), 0, stream, leaves, PBH, PBL,
                     ws, out);
}

// Round 5
// 132.552 us; speedup vs baseline: 1.1186x; 1.1186x over previous
//
#include <hip/hip_runtime.h>

typedef unsigned short u16;
typedef unsigned int u32;
typedef __attribute__((ext_vector_type(8))) __bf16 bf16x8;
typedef __attribute__((ext_vector_type(4))) float f32x4;

constexpr int NM = 8;

// ---- workspace layout (float offsets) ----
constexpr size_t OFF_QP  = 0;                    // fp32 Q^k [m][k-1][4096], k=1..12
constexpr size_t OFF_PI  = 393216;               // pi fp32 [m][64]
constexpr size_t OFF_PBH = 393728;               // P hi bf16 [e][m][c][d] (u16)
constexpr size_t OFF_PBL = OFF_PBH + 1015808;    // P lo

union FR { uint4 u; bf16x8 v; };

// split x -> hi (RNE bf16) + lo (trunc bf16 of residual)
__device__ __forceinline__ void split_bf16(float x, u16& h, u16& l) {
  u32 b = __float_as_uint(x);
  u32 hb = (b + 0x7fffu + ((b >> 16) & 1u)) & 0xffff0000u;
  h = (u16)(hb >> 16);
  float r = x - __uint_as_float(hb);
  l = (u16)(__float_as_uint(r) >> 16);
}

__device__ __forceinline__ void split8(const f32x4 a, const f32x4 b,
                                       uint4& hi, uint4& lo) {
  u16 h[8], l[8];
  split_bf16(a.x, h[0], l[0]); split_bf16(a.y, h[1], l[1]);
  split_bf16(a.z, h[2], l[2]); split_bf16(a.w, h[3], l[3]);
  split_bf16(b.x, h[4], l[4]); split_bf16(b.y, h[5], l[5]);
  split_bf16(b.z, h[6], l[6]); split_bf16(b.w, h[7], l[7]);
  hi.x = h[0] | ((u32)h[1] << 16); hi.y = h[2] | ((u32)h[3] << 16);
  hi.z = h[4] | ((u32)h[5] << 16); hi.w = h[6] | ((u32)h[7] << 16);
  lo.x = l[0] | ((u32)l[1] << 16); lo.y = l[2] | ((u32)l[3] << 16);
  lo.z = l[4] | ((u32)l[5] << 16); lo.w = l[6] | ((u32)l[7] << 16);
}

__device__ __forceinline__ void mfma3(f32x4& a, const uint4 ah, const uint4 al,
                                      const uint4 bh, const uint4 bl) {
  FR Ah, Al, Bh, Bl;
  Ah.u = ah; Al.u = al; Bh.u = bh; Bl.u = bl;
  a = __builtin_amdgcn_mfma_f32_16x16x32_bf16(Ah.v, Bh.v, a, 0, 0, 0);
  a = __builtin_amdgcn_mfma_f32_16x16x32_bf16(Ah.v, Bl.v, a, 0, 0, 0);
  a = __builtin_amdgcn_mfma_f32_16x16x32_bf16(Al.v, Bh.v, a, 0, 0, 0);
}

// XT format: 64 rows x 32 dwords (hi), +2048 (lo); 16B chunk j of row r at
// position ((j+r)&7) -> conflict-free b128 access.
__device__ __forceinline__ void xt_read2(const u32* b, int row, int chunk,
                                         uint4& hi, uint4& lo) {
  const int dw = (row << 5) + (((chunk + row) & 7) << 2);
  hi = *(const uint4*)&b[dw];
  lo = *(const uint4*)&b[2048 + dw];
}
__device__ __forceinline__ void xt_write4(u32* b, int row, int cp, int half,
                                          const f32x4 v) {
  u16 h[4], l[4];
  split_bf16(v.x, h[0], l[0]); split_bf16(v.y, h[1], l[1]);
  split_bf16(v.z, h[2], l[2]); split_bf16(v.w, h[3], l[3]);
  const int dw = (row << 5) + (((cp + row) & 7) << 2) + half * 2;
  uint2 hh, ll;
  hh.x = h[0] | ((u32)h[1] << 16); hh.y = h[2] | ((u32)h[3] << 16);
  ll.x = l[0] | ((u32)l[1] << 16); ll.y = l[2] | ((u32)l[3] << 16);
  *(uint2*)&b[dw] = hh;
  *(uint2*)&b[2048 + dw] = ll;
}

// Z = X*Y via split-bf16 MFMA on a 256-thread sub-block.
// RX = row-layout of X, CY = col-layout of Y. Writes Z fp32 to g (always),
// col-layout of Z to dstC, row-layout of Z (via Z^T = Y^T*X^T) to dstR.
__device__ void mmP(const u32* RX, const u32* CY, u32* dstC, u32* dstR,
                    float* __restrict__ g, int stid) {
  const int ln = stid & 15, kq = (stid >> 4) & 3, ct = stid >> 6;
  const f32x4 z = {0.f, 0.f, 0.f, 0.f};
  uint4 ah[2], al[2];
  #pragma unroll
  for (int kh = 0; kh < 2; ++kh)
    xt_read2(RX, ct * 16 + ln, kh * 4 + kq, ah[kh], al[kh]);
  f32x4 acc[4];
  #pragma unroll
  for (int bt = 0; bt < 4; ++bt) {
    acc[bt] = z;
    #pragma unroll
    for (int kh = 0; kh < 2; ++kh) {
      uint4 bh, bl;
      xt_read2(CY, bt * 16 + ln, kh * 4 + kq, bh, bl);
      mfma3(acc[bt], ah[kh], al[kh], bh, bl);
    }
  }
  #pragma unroll
  for (int bt = 0; bt < 4; ++bt) {
    #pragma unroll
    for (int r = 0; r < 4; ++r)
      g[(ct * 16 + kq * 4 + r) * 64 + bt * 16 + ln] = acc[bt][r];
    if (dstC) xt_write4(dstC, bt * 16 + ln, 2 * ct + (kq >> 1), kq & 1, acc[bt]);
  }
  if (dstR) {
    #pragma unroll
    for (int kh = 0; kh < 2; ++kh)
      xt_read2(CY, ct * 16 + ln, kh * 4 + kq, ah[kh], al[kh]);
    #pragma unroll
    for (int bt = 0; bt < 4; ++bt) {
      f32x4 a2 = z;
      #pragma unroll
      for (int kh = 0; kh < 2; ++kh) {
        uint4 bh, bl;
        xt_read2(RX, bt * 16 + ln, kh * 4 + kq, bh, bl);
        mfma3(a2, ah[kh], al[kh], bh, bl);
      }
      xt_write4(dstR, bt * 16 + ln, 2 * ct + (kq >> 1), kq & 1, a2);
    }
  }
}

// ---------------- K1: pi, Q, squaring ladder Q^2..Q^12 -> global fp32 ----
// 8 blocks x 1024 threads; 4 sub-blocks run independent matmuls per stage.
__global__ __launch_bounds__(1024) void k_power(const float* __restrict__ R_inv,
                                                const float* __restrict__ pi_inv,
                                                float* __restrict__ ws) {
  const int m = blockIdx.x;
  const int tid = threadIdx.x;
  __shared__ float pis[64];
  __shared__ float n2s;
  __shared__ __align__(16) float Qs[64 * 68];
  // 0..3: row-layout Q1,Q2,Q4,Q8; 4..7: col-layout Q1,Q2,Q3,Q4
  __shared__ __align__(16) u32 PB[8][4096];
  if (tid < 64) {
    float p = (tid < 63) ? pi_inv[m * 63 + tid] : 0.f;
    float v = p * p;
    #pragma unroll
    for (int off = 32; off; off >>= 1) v += __shfl_down(v, off, 64);
    if (tid == 0) n2s = v;
  }
  __syncthreads();
  if (tid < 64) {
    const float den = n2s + 1.f;
    const float x = (tid < 63) ? 2.f * pi_inv[m * 63 + tid] / den
                               : (n2s - 1.f) / den;
    const float pv = x * x;
    pis[tid] = pv;
    ws[OFF_PI + (size_t)m * 64 + tid] = pv;
  }
  __syncthreads();
  for (int idx = tid; idx < 4096; idx += 1024) {
    const int i = idx >> 6, j = idx & 63;
    float q = 0.f;
    if (i != j) {
      const int a = min(i, j), b = max(i, j);
      const int kk = a * (127 - a) / 2 + (b - a - 1);
      q = expf(R_inv[m * 2016 + kk]) * pis[j];
    }
    Qs[i * 68 + j] = q;
  }
  __syncthreads();
  if (tid < 64) {
    float s = 0.f;
    #pragma unroll 4
    for (int j4 = 0; j4 < 64; j4 += 4) {
      const f32x4 q = *(const f32x4*)&Qs[tid * 68 + j4];
      s += q.x + q.y + q.z + q.w;
    }
    Qs[tid * 68 + tid] = -s;
  }
  __syncthreads();
  float* g1 = ws + OFF_QP + (size_t)m * 12 * 4096;
  for (int idx = tid; idx < 4096; idx += 1024)
    g1[idx] = Qs[(idx >> 6) * 68 + (idx & 63)];
  if (tid < 512) {  // row-layout Q1
    const int i = tid >> 3, c = tid & 7;
    const f32x4 a = *(const f32x4*)&Qs[i * 68 + c * 8];
    const f32x4 b = *(const f32x4*)&Qs[i * 68 + c * 8 + 4];
    uint4 h, l;
    split8(a, b, h, l);
    const int dw = (i << 5) + (((c + i) & 7) << 2);
    *(uint4*)&PB[0][dw] = h;
    *(uint4*)&PB[0][2048 + dw] = l;
  } else {  // col-layout Q1
    const int t2 = tid - 512, j = t2 >> 3, c = t2 & 7;
    f32x4 a, b;
    a.x = Qs[(c * 8 + 0) * 68 + j]; a.y = Qs[(c * 8 + 1) * 68 + j];
    a.z = Qs[(c * 8 + 2) * 68 + j]; a.w = Qs[(c * 8 + 3) * 68 + j];
    b.x = Qs[(c * 8 + 4) * 68 + j]; b.y = Qs[(c * 8 + 5) * 68 + j];
    b.z = Qs[(c * 8 + 6) * 68 + j]; b.w = Qs[(c * 8 + 7) * 68 + j];
    uint4 h, l;
    split8(a, b, h, l);
    const int dw = (j << 5) + (((c + j) & 7) << 2);
    *(uint4*)&PB[4][dw] = h;
    *(uint4*)&PB[4][2048 + dw] = l;
  }
  __syncthreads();
  const int sub = tid >> 8, stid = tid & 255;
  if (sub == 0) mmP(PB[0], PB[4], PB[5], PB[1], g1 + 4096, stid);         // Q2
  __syncthreads();
  if (sub == 0) mmP(PB[1], PB[4], PB[6], nullptr, g1 + 2 * 4096, stid);   // Q3
  else if (sub == 1) mmP(PB[1], PB[5], PB[7], PB[2], g1 + 3 * 4096, stid);// Q4
  __syncthreads();
  if (sub == 0) mmP(PB[2], PB[4], nullptr, nullptr, g1 + 4 * 4096, stid); // Q5
  else if (sub == 1) mmP(PB[2], PB[5], nullptr, nullptr, g1 + 5 * 4096, stid);
  else if (sub == 2) mmP(PB[2], PB[6], nullptr, nullptr, g1 + 6 * 4096, stid);
  else mmP(PB[2], PB[7], nullptr, PB[3], g1 + 7 * 4096, stid);            // Q8
  __syncthreads();
  if (sub == 0) mmP(PB[3], PB[4], nullptr, nullptr, g1 + 8 * 4096, stid); // Q9
  else if (sub == 1) mmP(PB[3], PB[5], nullptr, nullptr, g1 + 9 * 4096, stid);
  else if (sub == 2) mmP(PB[3], PB[6], nullptr, nullptr, g1 + 10 * 4096, stid);
  else mmP(PB[3], PB[7], nullptr, nullptr, g1 + 11 * 4096, stid);         // Q12
}

// ---------------- K2: P = I + sum_k (t^k/k!) Q^k -> bf16 hi/lo ----------------
__global__ __launch_bounds__(256) void k_comb(const float* __restrict__ lengths,
                                              const float* __restrict__ ws,
                                              u16* __restrict__ ph_g,
                                              u16* __restrict__ pl_g) {
  const int e = blockIdx.x, m = blockIdx.y, tid = threadIdx.x;
  const float t = lengths[e];
  const float* qp = ws + OFF_QP + (size_t)m * 12 * 4096;
  u16* ph = ph_g + (((size_t)e * 8 + m) << 12);
  u16* pl = pl_g + (((size_t)e * 8 + m) << 12);
  float cf[12];
  cf[0] = t;
  #pragma unroll
  for (int k = 2; k <= 12; ++k) cf[k - 1] = cf[k - 2] * t / (float)k;
  #pragma unroll
  for (int rr = 0; rr < 4; ++rr) {
    const int off = rr * 1024 + tid * 4;
    const int i = off >> 6, j0 = off & 63;
    f32x4 a = {0.f, 0.f, 0.f, 0.f};
    if (i >= j0 && i < j0 + 4) a[i - j0] = 1.f;
    #pragma unroll
    for (int k = 1; k <= 12; ++k) {
      const f32x4 q = *(const f32x4*)&qp[(size_t)(k - 1) * 4096 + off];
      a += cf[k - 1] * q;
    }
    u16 h[4], l[4];
    split_bf16(a.x, h[0], l[0]); split_bf16(a.y, h[1], l[1]);
    split_bf16(a.z, h[2], l[2]); split_bf16(a.w, h[3], l[3]);
    ushort4 h4, l4;
    h4.x = h[0]; h4.y = h[1]; h4.z = h[2]; h4.w = h[3];
    l4.x = l[0]; l4.y = l[1]; l4.z = l[2]; l4.w = l[3];
    *(ushort4*)(ph + off) = h4;
    *(ushort4*)(pl + off) = l4;
  }
}

// ---------------- K3: fully-fused tree + final dot ----------------
// 256 blocks = (m = blk&7 [XCD affinity], btile of 32 cols) x 16 waves.
// Node slots: fp32 [b(32 rows)][d(64)], 16-chunk XOR swizzle; 16 x 8KB = 128KB.
// Slot map avoids read/write overlap within a level:
//   L0 out->p; L1 (2p,2p+1)->2p (row-disjoint per wave); L2 (4p,4p+2)->4p+1;
//   L3 (8p+1,8p+5)->8p; L4 reads (0,8).
__global__ __launch_bounds__(1024) void k_tree(
    const float* __restrict__ leaves, const u16* __restrict__ Phi,
    const u16* __restrict__ Plo, const float* __restrict__ ws,
    float* __restrict__ out) {
  const int m = blockIdx.x & 7, btile = blockIdx.x >> 3;
  const int tid = threadIdx.x, lane = tid & 63, w = tid >> 6;
  const int ln = lane & 15, kq = lane >> 4;
  __shared__ __align__(16) float slots[16 * 2048];
  __shared__ float part[2][4][16];
  const f32x4 z = {0.f, 0.f, 0.f, 0.f};

  auto do_pair = [&](int p, int eb, int in0, int instr, int out_slot, int bt0,
                     int nbt, int ct0, int nct, bool leaf, f32x4* rootout) {
    uint4 bh[2][2], bl[2][2];
    f32x4 acc0[4][2];
    #pragma unroll
    for (int s = 0; s < 2; ++s) {
      #pragma unroll
      for (int bi = 0; bi < 2; ++bi) {
        if (bi >= nbt) continue;
        const int r = (bt0 + bi) * 16 + ln;
        #pragma unroll
        for (int kh = 0; kh < 2; ++kh) {
          f32x4 xa, xb;
          if (leaf) {
            const float* g = leaves + (size_t)(btile * 32 + r) * 2048 +
                             (size_t)(eb + 2 * p + s) * 64 + kh * 32 + kq * 8;
            xa = __builtin_nontemporal_load((const f32x4*)g);
            xb = __builtin_nontemporal_load((const f32x4*)(g + 4));
          } else {
            const float* nb = slots + (in0 + s * instr) * 2048 + r * 64;
            const int cj = kh * 8 + kq * 2;
            xa = *(const f32x4*)&nb[((cj + r) & 15) << 2];
            xb = *(const f32x4*)&nb[((cj + 1 + r) & 15) << 2];
          }
          split8(xa, xb, bh[bi][kh], bl[bi][kh]);
        }
      }
      const size_t pbase = ((size_t)(eb + 2 * p + s) * 8 + m) << 12;
      #pragma unroll
      for (int ci = 0; ci < 4; ++ci) {
        if (ci >= nct) continue;
        const int ct = ct0 + ci;
        uint4 ah[2], al[2];
        #pragma unroll
        for (int kh = 0; kh < 2; ++kh) {
          const size_t off = pbase + (size_t)(ct * 16 + ln) * 64 + kh * 32 + kq * 8;
          ah[kh] = *(const uint4*)(Phi + off);
          al[kh] = *(const uint4*)(Plo + off);
        }
        #pragma unroll
        for (int bi = 0; bi < 2; ++bi) {
          if (bi >= nbt) continue;
          f32x4 a = z;
          #pragma unroll
          for (int kh = 0; kh < 2; ++kh)
            mfma3(a, ah[kh], al[kh], bh[bi][kh], bl[bi][kh]);
          if (s == 0) {
            acc0[ci][bi] = a;
          } else {
            const f32x4 pr = acc0[ci][bi] * a;
            if (rootout) {
              *rootout = pr;
            } else {
              const int r = (bt0 + bi) * 16 + ln;
              float* nb = slots + out_slot * 2048 + r * 64;
              *(f32x4*)&nb[((ct * 4 + kq + r) & 15) << 2] = pr;
            }
          }
        }
      }
    }
  };

  // L0: 16 pairs (leaves) -> slots 0..15; one pair per wave, 2 b-subtiles
  do_pair(w, 0, 0, 0, w, 0, 2, 0, 4, true, nullptr);
  __syncthreads();
  // L1: 8 pairs x 2 bt-waves: slots (2p,2p+1) -> 2p
  do_pair(w >> 1, 32, (w >> 1) * 2, 1, (w >> 1) * 2, w & 1, 1, 0, 4, false,
          nullptr);
  __syncthreads();
  // L2: 4 pairs x (bt, ct-half): slots (4p,4p+2) -> 4p+1
  do_pair(w >> 2, 48, (w >> 2) * 4, 2, (w >> 2) * 4 + 1, w & 1, 1,
          ((w >> 1) & 1) * 2, 2, false, nullptr);
  __syncthreads();
  // L3: 2 pairs x (bt, ct): slots (8p+1,8p+5) -> 8p
  do_pair(w >> 3, 56, (w >> 3) * 8 + 1, 4, (w >> 3) * 8, w & 1, 1, (w >> 1) & 3,
          1, false, nullptr);
  __syncthreads();
  // L4 root: slots (0,8); waves 0..7 = (bt, ct); fused dot with pi
  if (w < 8) {
    f32x4 prod = z;
    do_pair(0, 60, 0, 8, 0, w & 1, 1, w >> 1, 1, false, &prod);
    const f32x4 piv =
        *(const f32x4*)&ws[OFF_PI + (size_t)m * 64 + (w >> 1) * 16 + kq * 4];
    float v = prod.x * piv.x + prod.y * piv.y + prod.z * piv.z + prod.w * piv.w;
    v += __shfl_xor(v, 16, 64);
    v += __shfl_xor(v, 32, 64);
    if (lane < 16) part[w & 1][w >> 1][lane] = v;
  }
  __syncthreads();
  if (tid < 32) {
    const int bt = tid >> 4, bb = tid & 15;
    out[(size_t)(btile * 32 + tid) * 8 + m] =
        part[bt][0][bb] + part[bt][1][bb] + part[bt][2][bb] + part[bt][3][bb];
  }
}

extern "C" void kernel_launch(void* const* d_in, const int* in_sizes, int n_in,
                              void* d_out, int out_size, void* d_ws, size_t ws_size,
                              hipStream_t stream) {
  const float* leaves  = (const float*)d_in[0];  // (B, 32, 64)
  const float* R_inv   = (const float*)d_in[1];  // (8, 2016)
  const float* pi_inv  = (const float*)d_in[2];  // (8, 63)
  const float* lengths = (const float*)d_in[3];  // (62,)
  float* out = (float*)d_out;                    // (B, 8)
  float* ws  = (float*)d_ws;

  u16* PBH = (u16*)(ws + OFF_PBH);
  u16* PBL = (u16*)(ws + OFF_PBL);

  hipLaunchKernelGGL(k_power, dim3(NM), dim3(1024), 0, stream, R_inv, pi_inv, ws);
  hipLaunchKernelGGL(k_comb, dim3(62, NM), dim3(256), 0, stream, lengths, ws,
                     PBH, PBL);
  hipLaunchKernelGGL(k_tree, dim3(256), dim3(1024), 0, stream, leaves, PBH, PBL,
                     ws, out);
}

// Round 6
// 124.451 us; speedup vs baseline: 1.1914x; 1.0651x over previous
//
#include <hip/hip_runtime.h>

typedef unsigned short u16;
typedef unsigned int u32;
typedef __attribute__((ext_vector_type(8))) __bf16 bf16x8;
typedef __attribute__((ext_vector_type(4))) float f32x4;

// ---- workspace layout (float offsets) ----
constexpr size_t OFF_PI  = 0;                    // pi fp32 [m][64]
constexpr size_t OFF_PBH = 512;                  // P hi bf16 [e][m][c][d] (u16)
constexpr size_t OFF_PBL = OFF_PBH + 1015808;    // P lo

union FR { uint4 u; bf16x8 v; };

// split x -> hi (RNE bf16) + lo (trunc bf16 of residual)
__device__ __forceinline__ void split_bf16(float x, u16& h, u16& l) {
  u32 b = __float_as_uint(x);
  u32 hb = (b + 0x7fffu + ((b >> 16) & 1u)) & 0xffff0000u;
  h = (u16)(hb >> 16);
  float r = x - __uint_as_float(hb);
  l = (u16)(__float_as_uint(r) >> 16);
}

__device__ __forceinline__ void split8(const f32x4 a, const f32x4 b,
                                       uint4& hi, uint4& lo) {
  u16 h[8], l[8];
  split_bf16(a.x, h[0], l[0]); split_bf16(a.y, h[1], l[1]);
  split_bf16(a.z, h[2], l[2]); split_bf16(a.w, h[3], l[3]);
  split_bf16(b.x, h[4], l[4]); split_bf16(b.y, h[5], l[5]);
  split_bf16(b.z, h[6], l[6]); split_bf16(b.w, h[7], l[7]);
  hi.x = h[0] | ((u32)h[1] << 16); hi.y = h[2] | ((u32)h[3] << 16);
  hi.z = h[4] | ((u32)h[5] << 16); hi.w = h[6] | ((u32)h[7] << 16);
  lo.x = l[0] | ((u32)l[1] << 16); lo.y = l[2] | ((u32)l[3] << 16);
  lo.z = l[4] | ((u32)l[5] << 16); lo.w = l[6] | ((u32)l[7] << 16);
}

__device__ __forceinline__ void mfma3(f32x4& a, const uint4 ah, const uint4 al,
                                      const uint4 bh, const uint4 bl) {
  FR Ah, Al, Bh, Bl;
  Ah.u = ah; Al.u = al; Bh.u = bh; Bl.u = bl;
  a = __builtin_amdgcn_mfma_f32_16x16x32_bf16(Ah.v, Bh.v, a, 0, 0, 0);
  a = __builtin_amdgcn_mfma_f32_16x16x32_bf16(Ah.v, Bl.v, a, 0, 0, 0);
  a = __builtin_amdgcn_mfma_f32_16x16x32_bf16(Al.v, Bh.v, a, 0, 0, 0);
}

// bf16 hi/lo matrix buffer: 64 rows x 32 dwords hi + 2048 dwords lo; 16B chunk
// j of row r at ((j+r)&7) -> conflict-free b128.
__device__ __forceinline__ void xt_read2(const u32* b, int row, int chunk,
                                         uint4& hi, uint4& lo) {
  const int dw = (row << 5) + (((chunk + row) & 7) << 2);
  hi = *(const uint4*)&b[dw];
  lo = *(const uint4*)&b[2048 + dw];
}
__device__ __forceinline__ void xt_write4(u32* b, int row, int cp, int half,
                                          const f32x4 v) {
  u16 h[4], l[4];
  split_bf16(v.x, h[0], l[0]); split_bf16(v.y, h[1], l[1]);
  split_bf16(v.z, h[2], l[2]); split_bf16(v.w, h[3], l[3]);
  const int dw = (row << 5) + (((cp + row) & 7) << 2) + half * 2;
  uint2 hh, ll;
  hh.x = h[0] | ((u32)h[1] << 16); hh.y = h[2] | ((u32)h[3] << 16);
  ll.x = l[0] | ((u32)l[1] << 16); ll.y = l[2] | ((u32)l[3] << 16);
  *(uint2*)&b[dw] = hh;
  *(uint2*)&b[2048 + dw] = ll;
}

// ---------------- K1: pi, Q, squaring ladder, Taylor combine -> P hi/lo -----
// 128 blocks: m = blk&7 (XCD-affine so P lands in home XCD's L2), part = blk>>3.
// Each block redundantly computes the ladder (cheap); canonical 4 elems/thread
// of every power stay in registers; combine phase does its 4-edge share.
__global__ __launch_bounds__(1024) void k_pcomb(
    const float* __restrict__ R_inv, const float* __restrict__ pi_inv,
    const float* __restrict__ lengths, float* __restrict__ ws,
    u16* __restrict__ PBH, u16* __restrict__ PBL) {
  const int m = blockIdx.x & 7, prt = blockIdx.x >> 3;
  const int tid = threadIdx.x, lane = tid & 63, w = tid >> 6;
  const int ln = lane & 15, kq = lane >> 4;
  __shared__ float pis[64];
  __shared__ float n2s;
  __shared__ __align__(16) float Qs[64 * 68];  // later reused as fp32 staging
  __shared__ __align__(16) u32 PB[8][4096];    // 0..3 row Q1,Q2,Q4,Q8; 4..7 col Q1..Q4

  if (tid < 64) {
    float p = (tid < 63) ? pi_inv[m * 63 + tid] : 0.f;
    float v = p * p;
    #pragma unroll
    for (int off = 32; off; off >>= 1) v += __shfl_down(v, off, 64);
    if (tid == 0) n2s = v;
  }
  __syncthreads();
  if (tid < 64) {
    const float den = n2s + 1.f;
    const float x = (tid < 63) ? 2.f * pi_inv[m * 63 + tid] / den
                               : (n2s - 1.f) / den;
    const float pv = x * x;
    pis[tid] = pv;
    if (prt == 0) ws[OFF_PI + (size_t)m * 64 + tid] = pv;
  }
  __syncthreads();
  for (int idx = tid; idx < 4096; idx += 1024) {
    const int i = idx >> 6, j = idx & 63;
    float q = 0.f;
    if (i != j) {
      const int a = min(i, j), b = max(i, j);
      const int kk = a * (127 - a) / 2 + (b - a - 1);
      q = expf(R_inv[m * 2016 + kk]) * pis[j];
    }
    Qs[i * 68 + j] = q;
  }
  __syncthreads();
  if (tid < 64) {
    float s = 0.f;
    #pragma unroll 4
    for (int j4 = 0; j4 < 64; j4 += 4) {
      const f32x4 q = *(const f32x4*)&Qs[tid * 68 + j4];
      s += q.x + q.y + q.z + q.w;
    }
    Qs[tid * 68 + tid] = -s;
  }
  __syncthreads();
  // canonical Q1 + row/col Q1 layouts
  float q[12][4];
  const int ci0 = tid >> 4, cj0 = (tid & 15) * 4;
  #pragma unroll
  for (int r = 0; r < 4; ++r) q[0][r] = Qs[ci0 * 68 + cj0 + r];
  if (tid < 512) {
    const int i = tid >> 3, c = tid & 7;
    const f32x4 a = *(const f32x4*)&Qs[i * 68 + c * 8];
    const f32x4 b = *(const f32x4*)&Qs[i * 68 + c * 8 + 4];
    uint4 h, l;
    split8(a, b, h, l);
    const int dw = (i << 5) + (((c + i) & 7) << 2);
    *(uint4*)&PB[0][dw] = h;
    *(uint4*)&PB[0][2048 + dw] = l;
  } else {
    const int t2 = tid - 512, j = t2 >> 3, c = t2 & 7;
    f32x4 a, b;
    a.x = Qs[(c * 8 + 0) * 68 + j]; a.y = Qs[(c * 8 + 1) * 68 + j];
    a.z = Qs[(c * 8 + 2) * 68 + j]; a.w = Qs[(c * 8 + 3) * 68 + j];
    b.x = Qs[(c * 8 + 4) * 68 + j]; b.y = Qs[(c * 8 + 5) * 68 + j];
    b.z = Qs[(c * 8 + 6) * 68 + j]; b.w = Qs[(c * 8 + 7) * 68 + j];
    uint4 h, l;
    split8(a, b, h, l);
    const int dw = (j << 5) + (((c + j) & 7) << 2);
    *(uint4*)&PB[4][dw] = h;
    *(uint4*)&PB[4][2048 + dw] = l;
  }
  __syncthreads();

  const f32x4 z = {0.f, 0.f, 0.f, 0.f};
  const int ct = w >> 2, bt = w & 3;  // one 16x16 tile per wave (16 waves)
  // Z = X*Y; optional col-layout of Z; optional row-layout (via Z^T = Y^T X^T)
  auto mm = [&](const u32* RX, const u32* CY, u32* dstC, u32* dstR) {
    uint4 ah[2], al[2], bh[2], bl[2];
    #pragma unroll
    for (int kh = 0; kh < 2; ++kh) {
      xt_read2(RX, ct * 16 + ln, kh * 4 + kq, ah[kh], al[kh]);
      xt_read2(CY, bt * 16 + ln, kh * 4 + kq, bh[kh], bl[kh]);
    }
    f32x4 a = z;
    #pragma unroll
    for (int kh = 0; kh < 2; ++kh) mfma3(a, ah[kh], al[kh], bh[kh], bl[kh]);
    #pragma unroll
    for (int r = 0; r < 4; ++r)
      Qs[(ct * 16 + kq * 4 + r) * 64 + bt * 16 + ln] = a[r];
    if (dstC) xt_write4(dstC, bt * 16 + ln, 2 * ct + (kq >> 1), kq & 1, a);
    if (dstR) {
      #pragma unroll
      for (int kh = 0; kh < 2; ++kh) {
        xt_read2(CY, ct * 16 + ln, kh * 4 + kq, ah[kh], al[kh]);
        xt_read2(RX, bt * 16 + ln, kh * 4 + kq, bh[kh], bl[kh]);
      }
      f32x4 a2 = z;
      #pragma unroll
      for (int kh = 0; kh < 2; ++kh) mfma3(a2, ah[kh], al[kh], bh[kh], bl[kh]);
      xt_write4(dstR, bt * 16 + ln, 2 * ct + (kq >> 1), kq & 1, a2);
    }
  };
  auto step = [&](const u32* RX, const u32* CY, int k, u32* dstC, u32* dstR) {
    mm(RX, CY, dstC, dstR);
    __syncthreads();
    #pragma unroll
    for (int r = 0; r < 4; ++r) q[k - 1][r] = Qs[tid * 4 + r];
    __syncthreads();
  };
  step(PB[0], PB[4], 2, PB[5], PB[1]);    // Q2
  step(PB[1], PB[4], 3, PB[6], nullptr);  // Q3
  step(PB[1], PB[5], 4, PB[7], PB[2]);    // Q4
  step(PB[2], PB[4], 5, nullptr, nullptr);
  step(PB[2], PB[5], 6, nullptr, nullptr);
  step(PB[2], PB[6], 7, nullptr, nullptr);
  step(PB[2], PB[7], 8, nullptr, PB[3]);  // Q8
  step(PB[3], PB[4], 9, nullptr, nullptr);
  step(PB[3], PB[5], 10, nullptr, nullptr);
  step(PB[3], PB[6], 11, nullptr, nullptr);
  step(PB[3], PB[7], 12, nullptr, nullptr);

  // combine: this part's edges, all in registers
  #pragma unroll
  for (int ei = 0; ei < 4; ++ei) {
    const int e = prt * 4 + ei;
    if (e >= 62) break;
    const float t = lengths[e];
    float av[4] = {0.f, 0.f, 0.f, 0.f};
    const int dr = ci0 - cj0;
    if (dr >= 0 && dr < 4) av[dr] = 1.f;
    float cf = 1.f;
    #pragma unroll
    for (int k = 1; k <= 12; ++k) {
      cf *= t / (float)k;
      #pragma unroll
      for (int r = 0; r < 4; ++r) av[r] = fmaf(cf, q[k - 1][r], av[r]);
    }
    u16 h[4], l[4];
    split_bf16(av[0], h[0], l[0]); split_bf16(av[1], h[1], l[1]);
    split_bf16(av[2], h[2], l[2]); split_bf16(av[3], h[3], l[3]);
    const size_t base = (((size_t)e * 8 + m) << 12) + tid * 4;
    ushort4 h4, l4;
    h4.x = h[0]; h4.y = h[1]; h4.z = h[2]; h4.w = h[3];
    l4.x = l[0]; l4.y = l[1]; l4.z = l[2]; l4.w = l[3];
    *(ushort4*)(PBH + base) = h4;
    *(ushort4*)(PBL + base) = l4;
  }
}

// ---------------- K2: fully-fused tree + final dot ----------------
// 256 blocks = (m = blk&7 [XCD], btile of 32 cols) x 8 waves, <=256 VGPR.
// Nodes in LDS as interleaved h4|l4 16B chunks (16 chunks/row, XOR-swizzled):
// write = 1 b128, read = 2 b128 + register recombine (no VALU split).
// Slot map: node 32+i -> slot i (L0); 48+j -> 2j (L1); 56+j -> 4j (L2);
// 60+j -> 8j+1 (L3); root reads slots 1,9. Intra-level safety: each slot's
// readers either own the write (same-wave DS ordering) or touch disjoint rows.
__global__ __launch_bounds__(512, 2) void k_tree(
    const float* __restrict__ leaves, const u16* __restrict__ Phi,
    const u16* __restrict__ Plo, const float* __restrict__ ws,
    float* __restrict__ out) {
  const int m = blockIdx.x & 7, btile = blockIdx.x >> 3;
  const int tid = threadIdx.x, lane = tid & 63, w = tid >> 6;
  const int ln = lane & 15, kq = lane >> 4;
  __shared__ __align__(16) u32 slots[16 * 2048];  // 16 x (32 rows x 64 dwords)
  __shared__ float psum[2][4][16];
  const f32x4 z = {0.f, 0.f, 0.f, 0.f};

  auto node_read = [&](int slot, int row, int kh, uint4& bh, uint4& bl) {
    const int jc = kh * 8 + kq * 2;
    const u32* b = &slots[slot * 2048 + row * 64];
    const uint4 A = *(const uint4*)&b[((jc + row) & 15) << 2];
    const uint4 B = *(const uint4*)&b[((jc + 1 + row) & 15) << 2];
    bh.x = A.x; bh.y = A.y; bh.z = B.x; bh.w = B.y;
    bl.x = A.z; bl.y = A.w; bl.z = B.z; bl.w = B.w;
  };
  auto node_write = [&](int slot, int row, int jc, const f32x4 v) {
    u16 h[4], l[4];
    split_bf16(v.x, h[0], l[0]); split_bf16(v.y, h[1], l[1]);
    split_bf16(v.z, h[2], l[2]); split_bf16(v.w, h[3], l[3]);
    uint4 pk;
    pk.x = h[0] | ((u32)h[1] << 16); pk.y = h[2] | ((u32)h[3] << 16);
    pk.z = l[0] | ((u32)l[1] << 16); pk.w = l[2] | ((u32)l[3] << 16);
    *(uint4*)&slots[slot * 2048 + row * 64 + (((jc + row) & 15) << 2)] = pk;
  };

  auto do_pair = [&](int eb, int p, int s0, int s1, int outSlot, int bt0,
                     int nbt, int ct0, int nct, bool leaf, f32x4* rootout) {
    // phase 1: ALL B-fragments
    uint4 bfh[2][2][2], bfl[2][2][2];  // [sib][bi][kh]
    #pragma unroll
    for (int s = 0; s < 2; ++s)
      #pragma unroll
      for (int bi = 0; bi < 2; ++bi) {
        if (bi >= nbt) continue;
        const int row = (bt0 + bi) * 16 + ln;
        #pragma unroll
        for (int kh = 0; kh < 2; ++kh) {
          if (leaf) {
            const float* g = leaves + (size_t)(btile * 32 + row) * 2048 +
                             (size_t)(eb + 2 * p + s) * 64 + kh * 32 + kq * 8;
            const f32x4 xa = *(const f32x4*)g;
            const f32x4 xb = *(const f32x4*)(g + 4);
            split8(xa, xb, bfh[s][bi][kh], bfl[s][bi][kh]);
          } else {
            node_read(s ? s1 : s0, row, kh, bfh[s][bi][kh], bfl[s][bi][kh]);
          }
        }
      }
    // phase 2: ALL P-fragments for both siblings (deep load queue)
    uint4 ph[2][4][2], pl[2][4][2];  // [sib][ci][kh]
    #pragma unroll
    for (int s = 0; s < 2; ++s) {
      const size_t pb = ((size_t)(eb + 2 * p + s) * 8 + m) << 12;
      #pragma unroll
      for (int ci = 0; ci < 4; ++ci) {
        if (ci >= nct) continue;
        #pragma unroll
        for (int kh = 0; kh < 2; ++kh) {
          const size_t off =
              pb + (size_t)((ct0 + ci) * 16 + ln) * 64 + kh * 32 + kq * 8;
          ph[s][ci][kh] = *(const uint4*)(Phi + off);
          pl[s][ci][kh] = *(const uint4*)(Plo + off);
        }
      }
    }
    // phase 3: MFMA sibling 0
    f32x4 a0[4][2];
    #pragma unroll
    for (int ci = 0; ci < 4; ++ci) {
      if (ci >= nct) continue;
      #pragma unroll
      for (int bi = 0; bi < 2; ++bi) {
        if (bi >= nbt) continue;
        f32x4 a = z;
        #pragma unroll
        for (int kh = 0; kh < 2; ++kh)
          mfma3(a, ph[0][ci][kh], pl[0][ci][kh], bfh[0][bi][kh], bfl[0][bi][kh]);
        a0[ci][bi] = a;
      }
    }
    // phase 4: MFMA sibling 1, product, emit
    #pragma unroll
    for (int ci = 0; ci < 4; ++ci) {
      if (ci >= nct) continue;
      #pragma unroll
      for (int bi = 0; bi < 2; ++bi) {
        if (bi >= nbt) continue;
        f32x4 a = z;
        #pragma unroll
        for (int kh = 0; kh < 2; ++kh)
          mfma3(a, ph[1][ci][kh], pl[1][ci][kh], bfh[1][bi][kh], bfl[1][bi][kh]);
        const f32x4 pr = a0[ci][bi] * a;
        if (rootout)
          *rootout = pr;
        else
          node_write(outSlot, (bt0 + bi) * 16 + ln, (ct0 + ci) * 4 + kq, pr);
      }
    }
  };

  // L0: 16 pairs (leaves), 2 per wave -> slots 0..15
  do_pair(0, w, -1, -1, w, 0, 2, 0, 4, true, nullptr);
  do_pair(0, w + 8, -1, -1, w + 8, 0, 2, 0, 4, true, nullptr);
  __syncthreads();
  // L1: 8 pairs, 1/wave: slots (2w, 2w+1) -> 2w
  do_pair(32, w, 2 * w, 2 * w + 1, 2 * w, 0, 2, 0, 4, false, nullptr);
  __syncthreads();
  // L2: 4 pairs x 2 bi-waves: slots (4j, 4j+2) -> 4j
  {
    const int j = w >> 1, bi = w & 1;
    do_pair(48, j, 4 * j, 4 * j + 2, 4 * j, bi, 1, 0, 4, false, nullptr);
  }
  __syncthreads();
  // L3: 2 pairs x (bi, ct-half): slots (8j, 8j+4) -> 8j+1
  {
    const int j = w >> 2, bi = w & 1, ch = (w >> 1) & 1;
    do_pair(56, j, 8 * j, 8 * j + 4, 8 * j + 1, bi, 1, ch * 2, 2, false,
            nullptr);
  }
  __syncthreads();
  // L4 root: slots (1, 9); 8 waves = (bi, ct); fused dot with pi
  {
    f32x4 pr = z;
    do_pair(60, 0, 1, 9, -1, w & 1, 1, w >> 1, 1, false, &pr);
    const f32x4 piv =
        *(const f32x4*)&ws[OFF_PI + (size_t)m * 64 + (w >> 1) * 16 + kq * 4];
    float v = pr.x * piv.x + pr.y * piv.y + pr.z * piv.z + pr.w * piv.w;
    v += __shfl_xor(v, 16, 64);
    v += __shfl_xor(v, 32, 64);
    if (lane < 16) psum[w & 1][w >> 1][lane] = v;
  }
  __syncthreads();
  if (tid < 32) {
    const int bi = tid >> 4, bb = tid & 15;
    out[(size_t)(btile * 32 + tid) * 8 + m] =
        psum[bi][0][bb] + psum[bi][1][bb] + psum[bi][2][bb] + psum[bi][3][bb];
  }
}

extern "C" void kernel_launch(void* const* d_in, const int* in_sizes, int n_in,
                              void* d_out, int out_size, void* d_ws, size_t ws_size,
                              hipStream_t stream) {
  const float* leaves  = (const float*)d_in[0];  // (B, 32, 64)
  const float* R_inv   = (const float*)d_in[1];  // (8, 2016)
  const float* pi_inv  = (const float*)d_in[2];  // (8, 63)
  const float* lengths = (const float*)d_in[3];  // (62,)
  float* out = (float*)d_out;                    // (B, 8)
  float* ws  = (float*)d_ws;

  u16* PBH = (u16*)(ws + OFF_PBH);
  u16* PBL = (u16*)(ws + OFF_PBL);

  hipLaunchKernelGGL(k_pcomb, dim3(128), dim3(1024), 0, stream, R_inv, pi_inv,
                     lengths, ws, PBH, PBL);
  hipLaunchKernelGGL(k_tree, dim3(256), dim3(512), 0, stream, leaves, PBH, PBL,
                     ws, out);
}